// Round 1
// 283.848 us; speedup vs baseline: 1.1036x; 1.1036x over previous
//
#include <hip/hip_runtime.h>
#include <math.h>

#define SB 64
#define SS 512
#define SH 768
#define NT 36
#define TSTART 34
#define TSTOP 35
#define NC 16
#define CL 32
#define APAD 40

#define CFENCE() asm volatile("" ::: "memory")

__device__ __forceinline__ float wave_max_f(float v) {
#pragma unroll
    for (int off = 32; off > 0; off >>= 1) v = fmaxf(v, __shfl_xor(v, off, 64));
    return v;
}
__device__ __forceinline__ float wave_sum_f(float v) {
#pragma unroll
    for (int off = 32; off > 0; off >>= 1) v += __shfl_xor(v, off, 64);
    return v;
}
__device__ __forceinline__ float bcast0(float v) {
    return __uint_as_float(__builtin_amdgcn_readfirstlane(__float_as_uint(v)));
}

// ---------------- emissions ----------------
// emit[32768][36] = leaky_relu(Xg[32768][768] @ W[768][36] + b)
// 8-way K-split (96 floats/wave), 64 rows/block, 512 thr/block.
// Per-lane gathered float4 loads, prefetch depth 4; W reads are
// wave-uniform -> s_load. LDS reduce across the 8 waves, then
// float4-vectorized store through an LDS staging slab.
#define DOT4(pv, k4)                                                     \
    {                                                                    \
        const float* wr = Wq + (size_t)((k4) * 4) * NT;                  \
        _Pragma("unroll")                                                \
        for (int j = 0; j < NT; ++j) acc[j] += (pv).x * wr[j];           \
        _Pragma("unroll")                                                \
        for (int j = 0; j < NT; ++j) acc[j] += (pv).y * wr[NT + j];      \
        _Pragma("unroll")                                                \
        for (int j = 0; j < NT; ++j) acc[j] += (pv).z * wr[2 * NT + j];  \
        _Pragma("unroll")                                                \
        for (int j = 0; j < NT; ++j) acc[j] += (pv).w * wr[3 * NT + j];  \
    }

extern "C" __global__ __launch_bounds__(512) void k_emit(
    const float* __restrict__ x1, const int* __restrict__ hidx,
    const float* __restrict__ W, const float* __restrict__ bias,
    float* __restrict__ emit)
{
    __shared__ __align__(16) float red[8][64][37];   // +1 pad: conflict-free writes

    int tid  = threadIdx.x;
    int lane = tid & 63;
    int q    = __builtin_amdgcn_readfirstlane(tid >> 6);   // 0..7 K-chunk
    int gr   = blockIdx.x * 64 + lane;
    int b    = gr >> 9;
    const float4* xr = (const float4*)(x1 + (size_t)(b * SS + hidx[gr]) * SH) + q * 24;
    const float*  Wq = W + (size_t)q * 96 * NT;

    float acc[NT];
#pragma unroll
    for (int j = 0; j < NT; ++j) acc[j] = 0.f;

    // prefetch depth 4 over 24 float4 per lane
    float4 p0 = xr[0], p1 = xr[1], p2 = xr[2], p3 = xr[3];
    for (int kb = 0; kb < 20; kb += 4) {
        float4 n0 = xr[kb + 4];
        float4 n1 = xr[kb + 5];
        float4 n2 = xr[kb + 6];
        float4 n3 = xr[kb + 7];
        DOT4(p0, kb);
        DOT4(p1, kb + 1);
        DOT4(p2, kb + 2);
        DOT4(p3, kb + 3);
        p0 = n0; p1 = n1; p2 = n2; p3 = n3;
    }
    DOT4(p0, 20);
    DOT4(p1, 21);
    DOT4(p2, 22);
    DOT4(p3, 23);

#pragma unroll
    for (int j = 0; j < NT; ++j) red[q][lane][j] = acc[j];
    __syncthreads();

    int r = tid >> 2, g = tid & 3;
    float vout[9];
    if (tid < 256) {
#pragma unroll
        for (int jj = 0; jj < 9; ++jj) {
            int j = g * 9 + jj;
            float v = bias[j];
#pragma unroll
            for (int qq = 0; qq < 8; ++qq) v += red[qq][r][j];
            vout[jj] = v > 0.f ? v : 0.01f * v;
        }
    }
    __syncthreads();
    if (tid < 256) {
        float* st = &red[0][0][0];   // flat staging: 2304 floats fit in red[0] slab
#pragma unroll
        for (int jj = 0; jj < 9; ++jj) st[r * NT + g * 9 + jj] = vout[jj];
    }
    __syncthreads();
    {
        const float4* st4 = (const float4*)&red[0][0][0];
        float4* op = (float4*)(emit + (size_t)blockIdx.x * 64 * NT);
        for (int i = tid; i < 576; i += 512) op[i] = st4[i];
    }
}

// ---------------- chunked CRF scan ----------------
extern "C" __global__ __launch_bounds__(256) void k_scan(
    const float* __restrict__ emit, const int* __restrict__ hidx,
    const float* __restrict__ trans,
    float* __restrict__ A0,
    float* __restrict__ delta_ws, float* __restrict__ lse_local,
    float* __restrict__ score_local, int* __restrict__ ltag,
    unsigned char* __restrict__ bp, int pass)
{
    __shared__ float trl[NT * NT];
    __shared__ float els[4][1280];
    __shared__ float4 bc4[4][16];

    int tid  = threadIdx.x;
    int lane = tid & 63;
    int w    = __builtin_amdgcn_readfirstlane(tid >> 6);

    int wid  = blockIdx.x * 4 + w;
    int kind = wid >> 10;
    int rem  = wid & 1023;
    int b    = rem >> 4;
    int c    = rem & 15;

    const float* eb    = emit + (size_t)b * SS * NT;
    const float* ebase = eb + (size_t)c * CL * NT;
    float* elsw = els[w];

#pragma unroll
    for (int i = 0; i < 5; ++i) {
        __builtin_amdgcn_global_load_lds(
            (const __attribute__((address_space(1))) void*)(ebase + i * 256 + lane * 4),
            (__attribute__((address_space(3))) void*)(elsw + i * 256), 16, 0, 0);
    }
    for (int i = tid; i < NT * NT; i += 256) trl[i] = trans[i];

    int  jj  = lane < NT ? lane : NT - 1;
    bool act = lane < NT;

    int xm = 0;
    const int* hb = hidx + b * SS;
#pragma unroll
    for (int k = 0; k < SS / 64; ++k) xm = max(xm, hb[lane + 64 * k]);
#pragma unroll
    for (int off = 32; off > 0; off >>= 1) xm = max(xm, __shfl_xor(xm, off, 64));
    int xlen = xm;
    int cl   = (xlen >= 1) ? ((xlen - 1) >> 5) : 0;

    int tb = c * CL; if (tb < 1) tb = 1;
    int te = (c + 1) * CL; if (te > xlen) te = xlen; te -= 1;

    size_t aoff = (size_t)((((kind << 6) | b) << 4) | c) * APAD;
    int didx = (kind * SB + b) * NC + c;

    float alpha;
    if (c == 0)         alpha = act ? (eb[jj] + trans[TSTART * NT + jj]) : -1e30f;
    else if (pass == 0) alpha = act ? eb[(c * CL - 1) * NT + jj] : -1e30f;
    else                alpha = act ? A0[aoff - APAD + jj] : -1e30f;

    float a0prev = (pass == 1) ? A0[aoff] : 0.f;   // pass-0 end value (before overwrite)

    __syncthreads();

    float* bc = (float*)bc4[w];
    int t0 = c * CL;

    if (kind == 0) {
        float Ecol[NT];
#pragma unroll
        for (int i = 0; i < NT; ++i) Ecol[i] = __expf(trl[i * NT + jj]);
        for (int t = tb; t <= te; ++t) {
            float e_t = elsw[(t - t0) * NT + jj];
            float m = bcast0(alpha);
            float p = __expf(alpha - m);
            bc[lane] = p;
            CFENCE();
            __builtin_amdgcn_wave_barrier();
            float s0 = 0.f, s1 = 0.f, s2 = 0.f, s3 = 0.f;
#pragma unroll
            for (int k = 0; k < 9; ++k) {
                float4 pv = bc4[w][k];
                s0 += pv.x * Ecol[4 * k];
                s1 += pv.y * Ecol[4 * k + 1];
                s2 += pv.z * Ecol[4 * k + 2];
                s3 += pv.w * Ecol[4 * k + 3];
            }
            CFENCE();
            float anew = m + __logf((s0 + s1) + (s2 + s3)) + e_t;
            alpha = act ? anew : -1e30f;
        }
        if (act) A0[aoff + jj] = alpha;
        if (pass == 1) {
            float a0r = bcast0(a0prev);
            if (lane == 0) delta_ws[didx] = alpha - a0r;
            if (c == cl) {
                float ff = act ? (alpha + trl[jj * NT + TSTOP]) : -1e30f;
                float M = wave_max_f(ff);
                float ssum = wave_sum_f(__expf(ff - M));
                if (lane == 0) lse_local[b] = M + __logf(ssum);
            }
        }
    } else {
        float tcol[NT];
#pragma unroll
        for (int i = 0; i < NT; ++i) tcol[i] = trl[i * NT + jj];
        for (int t = tb; t <= te; ++t) {
            float e_t = elsw[(t - t0) * NT + jj];
            bc[lane] = alpha;
            CFENCE();
            __builtin_amdgcn_wave_barrier();
            float b0 = -1e30f, b1 = -1e30f, b2 = -1e30f, b3 = -1e30f;
            int   i0 = 0, i1 = 1, i2 = 2, i3 = 3;
#pragma unroll
            for (int k = 0; k < 9; ++k) {
                float4 dv = bc4[w][k];
                float c0 = dv.x + tcol[4 * k];
                float c1 = dv.y + tcol[4 * k + 1];
                float c2 = dv.z + tcol[4 * k + 2];
                float c3 = dv.w + tcol[4 * k + 3];
                if (c0 > b0) { b0 = c0; i0 = 4 * k; }
                if (c1 > b1) { b1 = c1; i1 = 4 * k + 1; }
                if (c2 > b2) { b2 = c2; i2 = 4 * k + 2; }
                if (c3 > b3) { b3 = c3; i3 = 4 * k + 3; }
            }
            CFENCE();
            float best = b0; int bi = i0;
            if (b1 > best || (b1 == best && i1 < bi)) { best = b1; bi = i1; }
            if (b2 > best || (b2 == best && i2 < bi)) { best = b2; bi = i2; }
            if (b3 > best || (b3 == best && i3 < bi)) { best = b3; bi = i3; }
            float dnew = best + e_t;
            alpha = act ? dnew : -1e30f;
            if (pass == 1 && act) bp[((size_t)b * SS + t) * 64 + jj] = (unsigned char)bi;
        }
        if (act) A0[aoff + jj] = alpha;
        if (pass == 1) {
            float a0r = bcast0(a0prev);
            if (lane == 0) delta_ws[didx] = alpha - a0r;
            if (c == cl) {
                float ff = act ? (alpha + trl[jj * NT + TSTOP]) : -1e30f;
                float bv = ff; int bi = lane;
#pragma unroll
                for (int off = 32; off > 0; off >>= 1) {
                    float ov = __shfl_xor(bv, off, 64);
                    int   oi = __shfl_xor(bi, off, 64);
                    if (ov > bv || (ov == bv && oi < bi)) { bv = ov; bi = oi; }
                }
                if (lane == 0) { score_local[b] = bv; ltag[b] = bi; }
            }
        }
    }
}

// ---------------- finalize ----------------
extern "C" __global__ __launch_bounds__(64) void k_final(
    const float* __restrict__ emit, const int* __restrict__ hidx,
    const int* __restrict__ tags, const float* __restrict__ trans,
    const float* __restrict__ delta_ws, const float* __restrict__ lse_local,
    const float* __restrict__ score_local, const int* __restrict__ ltag,
    const unsigned char* __restrict__ bp,
    float* __restrict__ lossp, float* __restrict__ path_out,
    float* __restrict__ score_out)
{
    __shared__ unsigned char bpl[SS * 64];
    int lane = threadIdx.x;
    int b    = blockIdx.x;

    const int4* src = (const int4*)(bp + (size_t)b * SS * 64);
    int4* dst = (int4*)bpl;
    for (int i = lane; i < SS * 4; i += 64) dst[i] = src[i];

    int xm = 0;
    const int* hb = hidx + b * SS;
#pragma unroll
    for (int k = 0; k < SS / 64; ++k) xm = max(xm, hb[lane + 64 * k]);
#pragma unroll
    for (int off = 32; off > 0; off >>= 1) xm = max(xm, __shfl_xor(xm, off, 64));
    int xlen = xm;
    int cl   = (xlen >= 1) ? ((xlen - 1) >> 5) : 0;

    float kf = 0.f, kv = 0.f;
    for (int k = 0; k < cl; ++k) {
        kf += delta_ws[(0 * SB + b) * NC + k];
        kv += delta_ws[(1 * SB + b) * NC + k];
    }

    const int* tg = tags + b * SS;
    float g = 0.f;
    for (int t = lane; t < SS; t += 64) {
        if (t < xlen) {
            int tt = tg[t];
            g += emit[((size_t)b * SS + t) * NT + tt];
            if (t >= 1) g += trans[tg[t - 1] * NT + tt];
        }
    }
    g = wave_sum_f(g);
    if (lane == 0) {
        int lt = (xlen >= 1) ? tg[xlen - 1] : tg[0];
        float gold = g + trans[TSTART * NT + tg[0]] + trans[lt * NT + TSTOP];
        lossp[b] = (lse_local[b] + kf) - gold;
        score_out[b] = score_local[b] + kv;
    }

    float* op = path_out + (size_t)b * SS;
    for (int t = lane; t < SS; t += 64) if (t >= xlen) op[t] = 0.f;
    int v = ltag[b];
    __syncthreads();
    if (xlen >= 1) {
        if (lane == 0) op[xlen - 1] = (float)v;
        int t = xlen - 1;
        while (t >= 1) {
            int n = t < 8 ? t : 8;
            int r0 = bpl[t * 64 + lane];
            int r1 = (n > 1) ? bpl[(t - 1) * 64 + lane] : 0;
            int r2 = (n > 2) ? bpl[(t - 2) * 64 + lane] : 0;
            int r3 = (n > 3) ? bpl[(t - 3) * 64 + lane] : 0;
            int r4 = (n > 4) ? bpl[(t - 4) * 64 + lane] : 0;
            int r5 = (n > 5) ? bpl[(t - 5) * 64 + lane] : 0;
            int r6 = (n > 6) ? bpl[(t - 6) * 64 + lane] : 0;
            int r7 = (n > 7) ? bpl[(t - 7) * 64 + lane] : 0;
            v = __shfl(r0, v, 64); if (lane == 0) op[t - 1] = (float)v;
            if (n > 1) { v = __shfl(r1, v, 64); if (lane == 0) op[t - 2] = (float)v; }
            if (n > 2) { v = __shfl(r2, v, 64); if (lane == 0) op[t - 3] = (float)v; }
            if (n > 3) { v = __shfl(r3, v, 64); if (lane == 0) op[t - 4] = (float)v; }
            if (n > 4) { v = __shfl(r4, v, 64); if (lane == 0) op[t - 5] = (float)v; }
            if (n > 5) { v = __shfl(r5, v, 64); if (lane == 0) op[t - 6] = (float)v; }
            if (n > 6) { v = __shfl(r6, v, 64); if (lane == 0) op[t - 7] = (float)v; }
            if (n > 7) { v = __shfl(r7, v, 64); if (lane == 0) op[t - 8] = (float)v; }
            t -= n;
        }
    }
}

extern "C" __global__ __launch_bounds__(64) void k_loss(
    const float* __restrict__ lossp, float* __restrict__ out)
{
    float v = lossp[threadIdx.x];
    v = wave_sum_f(v);
    if (threadIdx.x == 0) out[0] = v;
}

extern "C" void kernel_launch(void* const* d_in, const int* in_sizes, int n_in,
                              void* d_out, int out_size, void* d_ws, size_t ws_size,
                              hipStream_t stream)
{
    const float* x1    = (const float*)d_in[0];
    const int*   hidx  = (const int*)d_in[1];
    const int*   tags  = (const int*)d_in[2];
    const float* W     = (const float*)d_in[3];
    const float* bias  = (const float*)d_in[4];
    const float* trans = (const float*)d_in[5];
    float* out = (float*)d_out;

    float* emit        = (float*)d_ws;
    float* A0          = emit + (size_t)SB * SS * NT;
    float* delta_ws    = A0 + 2 * SB * NC * APAD;
    float* lse_local   = delta_ws + 2 * SB * NC;
    float* score_local = lse_local + SB;
    int*   ltag        = (int*)(score_local + SB);
    float* lossp       = (float*)(ltag + SB);
    unsigned char* bp  = (unsigned char*)(lossp + SB);

    hipLaunchKernelGGL(k_emit, dim3(SB * SS / 64), dim3(512), 0, stream,
                       x1, hidx, W, bias, emit);
    hipLaunchKernelGGL(k_scan, dim3(512), dim3(256), 0, stream,
                       emit, hidx, trans, A0, delta_ws, lse_local,
                       score_local, ltag, bp, 0);
    hipLaunchKernelGGL(k_scan, dim3(512), dim3(256), 0, stream,
                       emit, hidx, trans, A0, delta_ws, lse_local,
                       score_local, ltag, bp, 1);
    hipLaunchKernelGGL(k_final, dim3(SB), dim3(64), 0, stream,
                       emit, hidx, tags, trans, delta_ws, lse_local,
                       score_local, ltag, bp, lossp, out + 1, out + 1 + SB * SS);
    hipLaunchKernelGGL(k_loss, dim3(1), dim3(64), 0, stream, lossp, out);
}

// Round 2
// 224.083 us; speedup vs baseline: 1.3980x; 1.2667x over previous
//
#include <hip/hip_runtime.h>
#include <math.h>

#define SB 64
#define SS 512
#define SH 768
#define NT 36
#define TSTART 34
#define TSTOP 35
#define NC 16
#define CL 32
#define APAD 40

#define CFENCE() asm volatile("" ::: "memory")

__device__ __forceinline__ float wave_max_f(float v) {
#pragma unroll
    for (int off = 32; off > 0; off >>= 1) v = fmaxf(v, __shfl_xor(v, off, 64));
    return v;
}
__device__ __forceinline__ float wave_sum_f(float v) {
#pragma unroll
    for (int off = 32; off > 0; off >>= 1) v += __shfl_xor(v, off, 64);
    return v;
}
__device__ __forceinline__ float bcast0(float v) {
    return __uint_as_float(__builtin_amdgcn_readfirstlane(__float_as_uint(v)));
}

// ---------------- emissions ----------------
// emit[32768][36] = leaky_relu(Xg[32768][768] @ W[768][36] + b)
// 8-way K-split (96 floats/wave), 64 rows/block, 512 thr/block.
#define DOT4(pv, k4)                                                     \
    {                                                                    \
        const float* wr = Wq + (size_t)((k4) * 4) * NT;                  \
        _Pragma("unroll")                                                \
        for (int j = 0; j < NT; ++j) acc[j] += (pv).x * wr[j];           \
        _Pragma("unroll")                                                \
        for (int j = 0; j < NT; ++j) acc[j] += (pv).y * wr[NT + j];      \
        _Pragma("unroll")                                                \
        for (int j = 0; j < NT; ++j) acc[j] += (pv).z * wr[2 * NT + j];  \
        _Pragma("unroll")                                                \
        for (int j = 0; j < NT; ++j) acc[j] += (pv).w * wr[3 * NT + j];  \
    }

extern "C" __global__ __launch_bounds__(512) void k_emit(
    const float* __restrict__ x1, const int* __restrict__ hidx,
    const float* __restrict__ W, const float* __restrict__ bias,
    float* __restrict__ emit)
{
    __shared__ __align__(16) float red[8][64][37];

    int tid  = threadIdx.x;
    int lane = tid & 63;
    int q    = __builtin_amdgcn_readfirstlane(tid >> 6);   // 0..7 K-chunk
    int gr   = blockIdx.x * 64 + lane;
    int b    = gr >> 9;
    const float4* xr = (const float4*)(x1 + (size_t)(b * SS + hidx[gr]) * SH) + q * 24;
    const float*  Wq = W + (size_t)q * 96 * NT;

    float acc[NT];
#pragma unroll
    for (int j = 0; j < NT; ++j) acc[j] = 0.f;

    float4 p0 = xr[0], p1 = xr[1], p2 = xr[2], p3 = xr[3];
    for (int kb = 0; kb < 20; kb += 4) {
        float4 n0 = xr[kb + 4];
        float4 n1 = xr[kb + 5];
        float4 n2 = xr[kb + 6];
        float4 n3 = xr[kb + 7];
        DOT4(p0, kb);
        DOT4(p1, kb + 1);
        DOT4(p2, kb + 2);
        DOT4(p3, kb + 3);
        p0 = n0; p1 = n1; p2 = n2; p3 = n3;
    }
    DOT4(p0, 20);
    DOT4(p1, 21);
    DOT4(p2, 22);
    DOT4(p3, 23);

#pragma unroll
    for (int j = 0; j < NT; ++j) red[q][lane][j] = acc[j];
    __syncthreads();

    int r = tid >> 2, g = tid & 3;
    float vout[9];
    if (tid < 256) {
#pragma unroll
        for (int jj = 0; jj < 9; ++jj) {
            int j = g * 9 + jj;
            float v = bias[j];
#pragma unroll
            for (int qq = 0; qq < 8; ++qq) v += red[qq][r][j];
            vout[jj] = v > 0.f ? v : 0.01f * v;
        }
    }
    __syncthreads();
    if (tid < 256) {
        float* st = &red[0][0][0];
#pragma unroll
        for (int jj = 0; jj < 9; ++jj) st[r * NT + g * 9 + jj] = vout[jj];
    }
    __syncthreads();
    {
        const float4* st4 = (const float4*)&red[0][0][0];
        float4* op = (float4*)(emit + (size_t)blockIdx.x * 64 * NT);
        for (int i = tid; i < 576; i += 512) op[i] = st4[i];
    }
}

// ---------------- chunked CRF scan ----------------
extern "C" __global__ __launch_bounds__(256) void k_scan(
    const float* __restrict__ emit, const int* __restrict__ hidx,
    const float* __restrict__ trans,
    float* __restrict__ A0,
    float* __restrict__ delta_ws, float* __restrict__ lse_local,
    float* __restrict__ score_local, int* __restrict__ ltag,
    unsigned char* __restrict__ bp, int pass)
{
    __shared__ float trl[NT * NT];
    __shared__ float els[4][1280];
    __shared__ float4 bc4[4][16];

    int tid  = threadIdx.x;
    int lane = tid & 63;
    int w    = __builtin_amdgcn_readfirstlane(tid >> 6);

    int wid  = blockIdx.x * 4 + w;
    int kind = wid >> 10;
    int rem  = wid & 1023;
    int b    = rem >> 4;
    int c    = rem & 15;

    const float* eb    = emit + (size_t)b * SS * NT;
    const float* ebase = eb + (size_t)c * CL * NT;
    float* elsw = els[w];

#pragma unroll
    for (int i = 0; i < 5; ++i) {
        __builtin_amdgcn_global_load_lds(
            (const __attribute__((address_space(1))) void*)(ebase + i * 256 + lane * 4),
            (__attribute__((address_space(3))) void*)(elsw + i * 256), 16, 0, 0);
    }
    for (int i = tid; i < NT * NT; i += 256) trl[i] = trans[i];

    int  jj  = lane < NT ? lane : NT - 1;
    bool act = lane < NT;

    int xm = 0;
    const int* hb = hidx + b * SS;
#pragma unroll
    for (int k = 0; k < SS / 64; ++k) xm = max(xm, hb[lane + 64 * k]);
#pragma unroll
    for (int off = 32; off > 0; off >>= 1) xm = max(xm, __shfl_xor(xm, off, 64));
    int xlen = xm;
    int cl   = (xlen >= 1) ? ((xlen - 1) >> 5) : 0;

    int tb = c * CL; if (tb < 1) tb = 1;
    int te = (c + 1) * CL; if (te > xlen) te = xlen; te -= 1;

    size_t aoff = (size_t)((((kind << 6) | b) << 4) | c) * APAD;
    int didx = (kind * SB + b) * NC + c;

    float alpha;
    if (c == 0)         alpha = act ? (eb[jj] + trans[TSTART * NT + jj]) : -1e30f;
    else if (pass == 0) alpha = act ? eb[(c * CL - 1) * NT + jj] : -1e30f;
    else                alpha = act ? A0[aoff - APAD + jj] : -1e30f;

    float a0prev = (pass == 1) ? A0[aoff] : 0.f;

    __syncthreads();

    float* bc = (float*)bc4[w];
    int t0 = c * CL;

    if (kind == 0) {
        float Ecol[NT];
#pragma unroll
        for (int i = 0; i < NT; ++i) Ecol[i] = __expf(trl[i * NT + jj]);
        for (int t = tb; t <= te; ++t) {
            float e_t = elsw[(t - t0) * NT + jj];
            float m = bcast0(alpha);
            float p = __expf(alpha - m);
            bc[lane] = p;
            CFENCE();
            __builtin_amdgcn_wave_barrier();
            float s0 = 0.f, s1 = 0.f, s2 = 0.f, s3 = 0.f;
#pragma unroll
            for (int k = 0; k < 9; ++k) {
                float4 pv = bc4[w][k];
                s0 += pv.x * Ecol[4 * k];
                s1 += pv.y * Ecol[4 * k + 1];
                s2 += pv.z * Ecol[4 * k + 2];
                s3 += pv.w * Ecol[4 * k + 3];
            }
            CFENCE();
            float anew = m + __logf((s0 + s1) + (s2 + s3)) + e_t;
            alpha = act ? anew : -1e30f;
        }
        if (act) A0[aoff + jj] = alpha;
        if (pass == 1) {
            float a0r = bcast0(a0prev);
            if (lane == 0) delta_ws[didx] = alpha - a0r;
            if (c == cl) {
                float ff = act ? (alpha + trl[jj * NT + TSTOP]) : -1e30f;
                float M = wave_max_f(ff);
                float ssum = wave_sum_f(__expf(ff - M));
                if (lane == 0) lse_local[b] = M + __logf(ssum);
            }
        }
    } else {
        float tcol[NT];
#pragma unroll
        for (int i = 0; i < NT; ++i) tcol[i] = trl[i * NT + jj];
        for (int t = tb; t <= te; ++t) {
            float e_t = elsw[(t - t0) * NT + jj];
            bc[lane] = alpha;
            CFENCE();
            __builtin_amdgcn_wave_barrier();
            float b0 = -1e30f, b1 = -1e30f, b2 = -1e30f, b3 = -1e30f;
            int   i0 = 0, i1 = 1, i2 = 2, i3 = 3;
#pragma unroll
            for (int k = 0; k < 9; ++k) {
                float4 dv = bc4[w][k];
                float c0 = dv.x + tcol[4 * k];
                float c1 = dv.y + tcol[4 * k + 1];
                float c2 = dv.z + tcol[4 * k + 2];
                float c3 = dv.w + tcol[4 * k + 3];
                if (c0 > b0) { b0 = c0; i0 = 4 * k; }
                if (c1 > b1) { b1 = c1; i1 = 4 * k + 1; }
                if (c2 > b2) { b2 = c2; i2 = 4 * k + 2; }
                if (c3 > b3) { b3 = c3; i3 = 4 * k + 3; }
            }
            CFENCE();
            float best = b0; int bi = i0;
            if (b1 > best || (b1 == best && i1 < bi)) { best = b1; bi = i1; }
            if (b2 > best || (b2 == best && i2 < bi)) { best = b2; bi = i2; }
            if (b3 > best || (b3 == best && i3 < bi)) { best = b3; bi = i3; }
            float dnew = best + e_t;
            alpha = act ? dnew : -1e30f;
            if (pass == 1 && act) bp[((size_t)b * SS + t) * 64 + jj] = (unsigned char)bi;
        }
        if (act) A0[aoff + jj] = alpha;
        if (pass == 1) {
            float a0r = bcast0(a0prev);
            if (lane == 0) delta_ws[didx] = alpha - a0r;
            if (c == cl) {
                float ff = act ? (alpha + trl[jj * NT + TSTOP]) : -1e30f;
                float bv = ff; int bi = lane;
#pragma unroll
                for (int off = 32; off > 0; off >>= 1) {
                    float ov = __shfl_xor(bv, off, 64);
                    int   oi = __shfl_xor(bi, off, 64);
                    if (ov > bv || (ov == bv && oi < bi)) { bv = ov; bi = oi; }
                }
                if (lane == 0) { score_local[b] = bv; ltag[b] = bi; }
            }
        }
    }
}

// ---------------- finalize: parallel backtrace via map composition ----------------
// Backtrace tag_{t-1} = bp[t][tag_t] is function composition (associative).
// 16 waves each compose one 32-step chunk (serial depth 32, not 511),
// storing every intermediate composed map in LDS; a single thread stitches
// 16 chunk-exit maps; 512 threads then emit the whole path in parallel.
extern "C" __global__ __launch_bounds__(1024) void k_final(
    const float* __restrict__ emit, const int* __restrict__ hidx,
    const int* __restrict__ tags, const float* __restrict__ trans,
    const float* __restrict__ delta_ws, const float* __restrict__ lse_local,
    const float* __restrict__ score_local, const int* __restrict__ ltag,
    const unsigned char* __restrict__ bp,
    float* __restrict__ lossp, float* __restrict__ path_out,
    float* __restrict__ score_out)
{
    __shared__ unsigned char bpl[SS * 64];        // 32 KB: bp rows
    __shared__ unsigned char cmap[SS][40];        // 20 KB: composed maps, stride 40
    __shared__ unsigned char exitmap[NC][64];     // chunk-exit maps
    __shared__ float gred[16];
    __shared__ int   ent[NC];

    int tid  = threadIdx.x;
    int lane = tid & 63;
    int w    = tid >> 6;     // 0..15
    int b    = blockIdx.x;

    // stage bp -> LDS (2048 int4, 2 per thread)
    {
        const int4* src = (const int4*)(bp + (size_t)b * SS * 64);
        int4* dst = (int4*)bpl;
        for (int i = tid; i < SS * 4; i += 1024) dst[i] = src[i];
    }

    // xlen (redundant per wave; coalesced, L2-hot)
    int xm = 0;
    const int* hb = hidx + b * SS;
#pragma unroll
    for (int k = 0; k < SS / 64; ++k) xm = max(xm, hb[lane + 64 * k]);
#pragma unroll
    for (int off = 32; off > 0; off >>= 1) xm = max(xm, __shfl_xor(xm, off, 64));
    int xlen = xm;
    int cl   = (xlen >= 1) ? ((xlen - 1) >> 5) : 0;

    // gold score: waves 0..7, one t per thread (depth 1 instead of 8)
    float g = 0.f;
    const int* tg = tags + b * SS;
    if (tid < SS) {
        int t = tid;
        if (t < xlen) {
            int tt = tg[t];
            g += emit[((size_t)b * SS + t) * NT + tt];
            if (t >= 1) g += trans[tg[t - 1] * NT + tt];
        }
    }
    g = wave_sum_f(g);
    if (lane == 0) gred[w] = g;

    // delta sums: wave 8, lane-parallel (depth 1 instead of 15)
    float kf = 0.f, kv = 0.f;
    if (w == 8) {
        if (lane < cl) {
            kf = delta_ws[(0 * SB + b) * NC + lane];
            kv = delta_ws[(1 * SB + b) * NC + lane];
        }
        kf = wave_sum_f(kf);
        kv = wave_sum_f(kv);
    }

    __syncthreads();   // bpl staged; gred ready

    // loss/score finalize (tid 512 == wave 8 lane 0 holds kf,kv)
    if (tid == 512) {
        float gold = 0.f;
#pragma unroll
        for (int i = 0; i < 8; ++i) gold += gred[i];
        int tg0 = tg[0];
        int lt  = (xlen >= 1) ? tg[xlen - 1] : tg0;
        gold += trans[TSTART * NT + tg0] + trans[lt * NT + TSTOP];
        lossp[b]     = (lse_local[b] + kf) - gold;
        score_out[b] = score_local[b] + kv;
    }

    // compose: wave w handles chunk c = w
    {
        int c = w;
        if (xlen >= 1 && c <= cl) {
            int tb = (c == 0) ? 1 : c * CL;
            int te = c * CL + CL - 1; if (te > xlen - 1) te = xlen - 1;
            int m = lane;
            if (lane < NT) cmap[te][lane] = (unsigned char)m;   // identity at chunk top
            for (int t = te; t >= tb; --t) {
                m = bpl[t * 64 + m];
                if (lane < NT) {
                    if (t > tb || c == 0) cmap[t - 1][lane] = (unsigned char)m;
                    else                  exitmap[c][lane]  = (unsigned char)m;
                }
            }
        }
    }
    __syncthreads();

    // stitch chunk entry tags (<=16 dependent LDS reads)
    if (tid == 0 && xlen >= 1) {
        int e = ltag[b];
        for (int c2 = cl; c2 >= 0; --c2) {
            ent[c2] = e;
            if (c2 > 0) e = exitmap[c2][e];
        }
    }
    __syncthreads();

    // emit path: one t per thread
    if (tid < SS) {
        int t = tid;
        float* op = path_out + (size_t)b * SS;
        if (t >= xlen) op[t] = 0.f;
        else           op[t] = (float)cmap[t][ent[t >> 5]];
    }
}

extern "C" __global__ __launch_bounds__(64) void k_loss(
    const float* __restrict__ lossp, float* __restrict__ out)
{
    float v = lossp[threadIdx.x];
    v = wave_sum_f(v);
    if (threadIdx.x == 0) out[0] = v;
}

extern "C" void kernel_launch(void* const* d_in, const int* in_sizes, int n_in,
                              void* d_out, int out_size, void* d_ws, size_t ws_size,
                              hipStream_t stream)
{
    const float* x1    = (const float*)d_in[0];
    const int*   hidx  = (const int*)d_in[1];
    const int*   tags  = (const int*)d_in[2];
    const float* W     = (const float*)d_in[3];
    const float* bias  = (const float*)d_in[4];
    const float* trans = (const float*)d_in[5];
    float* out = (float*)d_out;

    float* emit        = (float*)d_ws;
    float* A0          = emit + (size_t)SB * SS * NT;
    float* delta_ws    = A0 + 2 * SB * NC * APAD;
    float* lse_local   = delta_ws + 2 * SB * NC;
    float* score_local = lse_local + SB;
    int*   ltag        = (int*)(score_local + SB);
    float* lossp       = (float*)(ltag + SB);
    unsigned char* bp  = (unsigned char*)(lossp + SB);

    hipLaunchKernelGGL(k_emit, dim3(SB * SS / 64), dim3(512), 0, stream,
                       x1, hidx, W, bias, emit);
    hipLaunchKernelGGL(k_scan, dim3(512), dim3(256), 0, stream,
                       emit, hidx, trans, A0, delta_ws, lse_local,
                       score_local, ltag, bp, 0);
    hipLaunchKernelGGL(k_scan, dim3(512), dim3(256), 0, stream,
                       emit, hidx, trans, A0, delta_ws, lse_local,
                       score_local, ltag, bp, 1);
    hipLaunchKernelGGL(k_final, dim3(SB), dim3(1024), 0, stream,
                       emit, hidx, tags, trans, delta_ws, lse_local,
                       score_local, ltag, bp, lossp, out + 1, out + 1 + SB * SS);
    hipLaunchKernelGGL(k_loss, dim3(1), dim3(64), 0, stream, lossp, out);
}